// Round 2
// baseline (1014.178 us; speedup 1.0000x reference)
//
#include <hip/hip_runtime.h>
#include <hip/hip_bf16.h>

// GQA block, MI355X/gfx950. Round 4: round-3 minus the nontemporal att store.
//   (nt stores bypassed L2 write-combining: WRITE_SIZE 528MB->1.03GB, FETCH +325MB,
//    attn 382->520us. Regular stores let L2 assemble the 16B/lane dwordx4 stores
//    into full lines. Everything else from round 3 kept: per-lane online stats,
//    single end-of-loop shfl reduce, early V-load staging, exp2 w/ folded log2e.)
//   prep:   x -> bf16; pack Wq|Wk|Wv transposed [n][c] bf16; Wo transposed [n][k] bf16
//   gemm<0>: xb @ WqkvT -> Qb [h][s][64] (x 0.125*log2e, +bq), Kb (+bk), VTb [h][64][s] (+bv)
//   attn:   grid (256 q-tiles of 16 rows, 8 heads). 4 waves/block each own a 1024-key
//           quarter; zero barriers in the K loops; K/V direct from global (L2-resident).
//   gemm<1>: OAb @ WobT + bo -> out fp32
// MFMA 16x16x32 bf16 layouts:
//   A: lane holds A[m=lane&15][k=quad*8+j]   B: B[k=quad*8+j][n=lane&15]
//   C/D: D[row=quad*4+reg][col=lane&15]

#define DIM   768
#define Sc    4096
// 0.125 * log2(e): QK^T scores land in log2 domain, softmax via exp2
#define QSCALE 0.180336880111120419f

typedef __bf16 bfrag __attribute__((ext_vector_type(8)));
typedef float  facc  __attribute__((ext_vector_type(4)));

#define MFMA_BF16(a,b,c) __builtin_amdgcn_mfma_f32_16x16x32_bf16((a),(b),(c),0,0,0)

// ---------------------------------------------------------------- prep
__global__ __launch_bounds__(256) void prep_kernel(
    const float* __restrict__ x,  const float* __restrict__ Wq,
    const float* __restrict__ Wk, const float* __restrict__ Wv,
    const float* __restrict__ Wo,
    __bf16* __restrict__ xb, __bf16* __restrict__ WqkvT, __bf16* __restrict__ WobT)
{
  int i = blockIdx.x * 256 + threadIdx.x;
  const int NX = Sc * DIM;      // 3145728
  const int NW = DIM * DIM;     // 589824
  if (i < NX) { xb[i] = (__bf16)x[i]; return; }
  i -= NX;
  if (i < NW) {                 // WqkvT[n][c]
    int n = i / DIM, c = i - n * DIM;
    float v;
    if (n < 512)      v = Wq[c * 512 + n];
    else if (n < 640) v = Wk[c * 128 + (n - 512)];
    else              v = Wv[c * 128 + (n - 640)];
    WqkvT[i] = (__bf16)v;
    return;
  }
  i -= NW;
  {                             // WobT[n][k], n<768, k<512
    int n = i / 512, k = i - n * 512;
    WobT[i] = (__bf16)Wo[k * DIM + n];
  }
}

// ---------------------------------------------------------------- gemm
// C[M=4096, N] = A[M,Kd] @ BT[N,Kd]^T. 64x64 block tile, 4 waves x (16r x 64c), BK=64.
// MODE 0: QKV epilogue (scatter to Qb/Kb/VTb, bias, Q scale QSCALE). MODE 1: fp32 out + b0.
template<int MODE>
__global__ __launch_bounds__(256) void gemm_kernel(
    const __bf16* __restrict__ A, const __bf16* __restrict__ BT, int Kd,
    const float* __restrict__ b0, const float* __restrict__ b1, const float* __restrict__ b2,
    __bf16* __restrict__ Qb, __bf16* __restrict__ Kb, __bf16* __restrict__ VTb,
    float* __restrict__ Cout)
{
  const int tid  = threadIdx.x;
  const int w    = tid >> 6;
  const int lane = tid & 63;
  const int i16  = lane & 15;
  const int quad = lane >> 4;
  const int n0   = blockIdx.x * 64;
  const int m0   = blockIdx.y * 64;

  __shared__ __attribute__((aligned(16))) __bf16 Al[64 * 72];
  __shared__ __attribute__((aligned(16))) __bf16 Bl[64 * 72];

  facc acc[4];
#pragma unroll
  for (int nt = 0; nt < 4; ++nt) acc[nt] = (facc){0.f, 0.f, 0.f, 0.f};

  const int nkt = Kd >> 6;
  for (int kt = 0; kt < nkt; ++kt) {
#pragma unroll
    for (int it = 0; it < 2; ++it) {       // A tile: 64 rows x 64k = 512 x 16B chunks
      int idx = tid + it * 256;
      int r = idx >> 3, ch = idx & 7;
      *(uint4*)&Al[r * 72 + ch * 8] =
          *(const uint4*)(A + (size_t)(m0 + r) * Kd + (kt * 64 + ch * 8));
    }
#pragma unroll
    for (int it = 0; it < 2; ++it) {       // BT tile
      int idx = tid + it * 256;
      int r = idx >> 3, ch = idx & 7;
      *(uint4*)&Bl[r * 72 + ch * 8] =
          *(const uint4*)(BT + (size_t)(n0 + r) * Kd + (kt * 64 + ch * 8));
    }
    __syncthreads();
#pragma unroll
    for (int ks = 0; ks < 2; ++ks) {
      bfrag a = *(const bfrag*)&Al[(w * 16 + i16) * 72 + ks * 32 + quad * 8];
#pragma unroll
      for (int nt = 0; nt < 4; ++nt) {
        bfrag b = *(const bfrag*)&Bl[(nt * 16 + i16) * 72 + ks * 32 + quad * 8];
        acc[nt] = MFMA_BF16(a, b, acc[nt]);
      }
    }
    __syncthreads();
  }

#pragma unroll
  for (int nt = 0; nt < 4; ++nt) {
    const int n = n0 + nt * 16 + i16;
    const int rbase = m0 + w * 16 + quad * 4;
    if (MODE == 0) {
      float bias;
      if (n < 512)      bias = b0[n];
      else if (n < 640) bias = b1[n - 512];
      else              bias = b2[n - 640];
#pragma unroll
      for (int reg = 0; reg < 4; ++reg) {
        float v = acc[nt][reg] + bias;
        int row = rbase + reg;
        if (n < 512) {                    // Q: fold 1/sqrt(64) * log2(e)
          int hh = n >> 6, d = n & 63;
          Qb[((size_t)hh * Sc + row) * 64 + d] = (__bf16)(v * QSCALE);
        } else if (n < 640) {             // K
          int hh = (n - 512) >> 6, d = n & 63;
          Kb[((size_t)hh * Sc + row) * 64 + d] = (__bf16)v;
        } else {                          // V stored transposed: VT[h][d][s]
          int hh = (n - 640) >> 6, d = n & 63;
          VTb[(size_t)hh * 64 * Sc + (size_t)d * Sc + row] = (__bf16)v;
        }
      }
    } else {
      float bias = b0[n];
#pragma unroll
      for (int reg = 0; reg < 4; ++reg)
        Cout[(size_t)(rbase + reg) * DIM + n] = acc[nt][reg] + bias;
    }
  }
}

// ---------------------------------------------------------------- attention
// grid (Sc/16 = 256, 8 heads), 256 thr = 4 waves. Block = 16 q-rows; wave w owns
// keys [w*1024, (w+1)*1024). No barriers inside the K loops.
#define PFSTRIDE 68            // fp32 row stride (64 + 4 pad)
#define PFWAVE   (16 * PFSTRIDE + 4)   // 1092: per-wave region, +4 breaks w-stride conflicts

__global__ __launch_bounds__(256, 6) void attn_kernel(
    const __bf16* __restrict__ Qb, const __bf16* __restrict__ Kb,
    const __bf16* __restrict__ VTb,
    float* __restrict__ att, __bf16* __restrict__ OAb)
{
  const int tid  = threadIdx.x;
  const int w    = tid >> 6;
  const int lane = tid & 63;
  const int i16  = lane & 15;
  const int quad = lane >> 4;
  const int h    = blockIdx.y;
  const int kvh  = h >> 2;          // n_rep = 4
  const int q0   = blockIdx.x * 16;

  __shared__ __attribute__((aligned(16))) float Pf[4 * PFWAVE];  // ~17.5 KB
  __shared__ float SM[4][16], SL[4][16];

  const __bf16* Kbase = Kb  + (size_t)kvh * Sc * 64;
  const __bf16* Vbase = VTb + (size_t)kvh * 64 * Sc;

  // Q A-fragments (already scaled by 0.125*log2e), 16 rows
  bfrag qf[2];
#pragma unroll
  for (int ks = 0; ks < 2; ++ks)
    qf[ks] = *(const bfrag*)(Qb + ((size_t)h * Sc + q0 + i16) * 64 + ks * 32 + quad * 8);

  const int key0 = w * 1024;

  // ---------------- phase 1: PER-LANE online stats over this wave's quarter ------
  // C layout: lane holds rows quad*4+r, cols nt*16+i16. Keep max/sum per lane
  // (over this lane's 4 columns per tile); cross-lane reduce ONCE at the end.
  float mrun[4], lrun[4];
#pragma unroll
  for (int r = 0; r < 4; ++r) { mrun[r] = -1e30f; lrun[r] = 0.f; }

  for (int kt = 0; kt < 16; ++kt) {
    const int kb0 = key0 + kt * 64;
    facc s[4];
#pragma unroll
    for (int nt = 0; nt < 4; ++nt) s[nt] = (facc){0.f, 0.f, 0.f, 0.f};
    __builtin_amdgcn_s_setprio(1);
#pragma unroll
    for (int ks = 0; ks < 2; ++ks)
#pragma unroll
      for (int nt = 0; nt < 4; ++nt) {
        bfrag kf = *(const bfrag*)(Kbase + (size_t)(kb0 + nt * 16 + i16) * 64 + ks * 32 + quad * 8);
        s[nt] = MFMA_BF16(qf[ks], kf, s[nt]);
      }
    __builtin_amdgcn_s_setprio(0);
#pragma unroll
    for (int r = 0; r < 4; ++r) {
      float t0 = s[0][r], t1 = s[1][r], t2 = s[2][r], t3 = s[3][r];
      float tm   = fmaxf(fmaxf(t0, t1), fmaxf(t2, t3));
      float mnew = fmaxf(mrun[r], tm);
      float ts = exp2f(t0 - mnew) + exp2f(t1 - mnew)
               + exp2f(t2 - mnew) + exp2f(t3 - mnew);
      lrun[r] = lrun[r] * exp2f(mrun[r] - mnew) + ts;
      mrun[r] = mnew;
    }
  }

  // single cross-lane reduce (16 lanes sharing each row), then cross-wave combine
#pragma unroll
  for (int r = 0; r < 4; ++r) {
    float m = mrun[r];
    m = fmaxf(m, __shfl_xor(m, 1));
    m = fmaxf(m, __shfl_xor(m, 2));
    m = fmaxf(m, __shfl_xor(m, 4));
    m = fmaxf(m, __shfl_xor(m, 8));
    float l = lrun[r] * exp2f(mrun[r] - m);
    l += __shfl_xor(l, 1);
    l += __shfl_xor(l, 2);
    l += __shfl_xor(l, 4);
    l += __shfl_xor(l, 8);
    if (i16 == 0) { SM[w][quad * 4 + r] = m; SL[w][quad * 4 + r] = l; }
  }
  __syncthreads();

  float mglob[4], linv[4];
#pragma unroll
  for (int r = 0; r < 4; ++r) {
    const int rr = quad * 4 + r;
    float m0v = SM[0][rr], m1v = SM[1][rr], m2v = SM[2][rr], m3v = SM[3][rr];
    float mg = fmaxf(fmaxf(m0v, m1v), fmaxf(m2v, m3v));
    float lg = SL[0][rr] * exp2f(m0v - mg) + SL[1][rr] * exp2f(m1v - mg)
             + SL[2][rr] * exp2f(m2v - mg) + SL[3][rr] * exp2f(m3v - mg);
    mglob[r] = mg;
    linv[r]  = 1.f / lg;
  }

  facc oacc[4];
#pragma unroll
  for (int nt = 0; nt < 4; ++nt) oacc[nt] = (facc){0.f, 0.f, 0.f, 0.f};

  float* attb = att + (size_t)h * Sc * Sc;
  float* Pw   = Pf + w * PFWAVE;

  // ---------------- phase 2: recompute S, write att, PV ----------------
  for (int kt = 0; kt < 16; ++kt) {
    const int kb0 = key0 + kt * 64;
    facc s[4];
#pragma unroll
    for (int nt = 0; nt < 4; ++nt) s[nt] = (facc){0.f, 0.f, 0.f, 0.f};
    __builtin_amdgcn_s_setprio(1);
#pragma unroll
    for (int ks = 0; ks < 2; ++ks)
#pragma unroll
      for (int nt = 0; nt < 4; ++nt) {
        bfrag kf = *(const bfrag*)(Kbase + (size_t)(kb0 + nt * 16 + i16) * 64 + ks * 32 + quad * 8);
        s[nt] = MFMA_BF16(qf[ks], kf, s[nt]);
      }
    __builtin_amdgcn_s_setprio(0);

    // issue first half of V loads NOW: latency hides under softmax + LDS transpose
    bfrag vf0[4];
#pragma unroll
    for (int nt = 0; nt < 4; ++nt)
      vf0[nt] = *(const bfrag*)(Vbase + (size_t)(nt * 16 + i16) * Sc + kb0 + quad * 8);

    // normalized probabilities -> per-wave fp32 LDS tile (C-layout writes)
#pragma unroll
    for (int nt = 0; nt < 4; ++nt)
#pragma unroll
      for (int r = 0; r < 4; ++r)
        Pw[(quad * 4 + r) * PFSTRIDE + nt * 16 + i16] =
            exp2f(s[nt][r] - mglob[r]) * linv[r];

    // second half of V loads in flight while we pull A-layout fragments back
    bfrag vf1[4];
#pragma unroll
    for (int nt = 0; nt < 4; ++nt)
      vf1[nt] = *(const bfrag*)(Vbase + (size_t)(nt * 16 + i16) * Sc + kb0 + 32 + quad * 8);

    // A-layout fragments out of the same tile (same wave: no barrier)
    bfrag pa[2];
#pragma unroll
    for (int ks = 0; ks < 2; ++ks) {
      facc p0 = *(const facc*)&Pw[i16 * PFSTRIDE + ks * 32 + quad * 8];
      facc p1 = *(const facc*)&Pw[i16 * PFSTRIDE + ks * 32 + quad * 8 + 4];
      bfrag t;
      t[0] = (__bf16)p0[0]; t[1] = (__bf16)p0[1]; t[2] = (__bf16)p0[2]; t[3] = (__bf16)p0[3];
      t[4] = (__bf16)p1[0]; t[5] = (__bf16)p1[1]; t[6] = (__bf16)p1[2]; t[7] = (__bf16)p1[3];
      pa[ks] = t;
    }

    __builtin_amdgcn_s_setprio(1);
#pragma unroll
    for (int nt = 0; nt < 4; ++nt) oacc[nt] = MFMA_BF16(pa[0], vf0[nt], oacc[nt]);
#pragma unroll
    for (int nt = 0; nt < 4; ++nt) oacc[nt] = MFMA_BF16(pa[1], vf1[nt], oacc[nt]);
    __builtin_amdgcn_s_setprio(0);

    // coalesced att store: 4 x dwordx4, 256B per quad-row (regular stores: L2
    // assembles full lines across the 4 waves' disjoint column chunks)
#pragma unroll
    for (int it = 0; it < 4; ++it) {
      int flat = it * 64 + lane;
      int row = flat >> 4, c4 = flat & 15;
      facc v = *(const facc*)&Pw[row * PFSTRIDE + c4 * 4];
      *(facc*)&attb[(size_t)(q0 + row) * Sc + kb0 + c4 * 4] = v;
    }
  }

  // ---------------- reduce O partials across waves (reuse Pf) ----------------
#pragma unroll
  for (int nt = 0; nt < 4; ++nt)
#pragma unroll
    for (int r = 0; r < 4; ++r)
      Pw[(quad * 4 + r) * PFSTRIDE + nt * 16 + i16] = oacc[nt][r];
  __syncthreads();
#pragma unroll
  for (int it = 0; it < 4; ++it) {
    int e = it * 256 + tid;
    int row = e >> 6, d = e & 63;
    float sum = Pf[0 * PFWAVE + row * PFSTRIDE + d] + Pf[1 * PFWAVE + row * PFSTRIDE + d]
              + Pf[2 * PFWAVE + row * PFSTRIDE + d] + Pf[3 * PFWAVE + row * PFSTRIDE + d];
    OAb[(size_t)(q0 + row) * 512 + h * 64 + d] = (__bf16)sum;
  }
}

// ---------------------------------------------------------------- launch
extern "C" void kernel_launch(void* const* d_in, const int* in_sizes, int n_in,
                              void* d_out, int out_size, void* d_ws, size_t ws_size,
                              hipStream_t stream) {
  const float* x  = (const float*)d_in[0];
  const float* Wq = (const float*)d_in[1];
  const float* bq = (const float*)d_in[2];
  const float* Wk = (const float*)d_in[3];
  const float* bk = (const float*)d_in[4];
  const float* Wv = (const float*)d_in[5];
  const float* bv = (const float*)d_in[6];
  const float* Wo = (const float*)d_in[7];
  const float* bo = (const float*)d_in[8];

  float* out = (float*)d_out;
  float* att = out + (size_t)Sc * DIM;   // outputs concatenated: out then att

  char* ws = (char*)d_ws;
  size_t off = 0;
  __bf16* xb    = (__bf16*)(ws + off); off += (size_t)Sc * DIM * 2;
  __bf16* WqkvT = (__bf16*)(ws + off); off += (size_t)DIM * DIM * 2;
  __bf16* WobT  = (__bf16*)(ws + off); off += (size_t)DIM * 512 * 2;
  __bf16* Qb    = (__bf16*)(ws + off); off += (size_t)8 * Sc * 64 * 2;
  __bf16* Kb    = (__bf16*)(ws + off); off += (size_t)2 * Sc * 64 * 2;
  __bf16* VTb   = (__bf16*)(ws + off); off += (size_t)2 * 64 * Sc * 2;
  __bf16* OAb   = (__bf16*)(ws + off); off += (size_t)Sc * 512 * 2;

  prep_kernel<<<16128, 256, 0, stream>>>(x, Wq, Wk, Wv, Wo, xb, WqkvT, WobT);
  gemm_kernel<0><<<dim3(12, 64), 256, 0, stream>>>(xb, WqkvT, 768, bq, bk, bv,
                                                   Qb, Kb, VTb, nullptr);
  attn_kernel<<<dim3(256, 8), 256, 0, stream>>>(Qb, Kb, VTb, att, OAb);
  gemm_kernel<1><<<dim3(12, 64), 256, 0, stream>>>(OAb, WobT, 512, bo, nullptr, nullptr,
                                                   nullptr, nullptr, nullptr, out);
}

// Round 3
// 878.432 us; speedup vs baseline: 1.1545x; 1.1545x over previous
//
#include <hip/hip_runtime.h>
#include <hip/hip_bf16.h>

// GQA block, MI355X/gfx950. Round 5: round-0 attn structure restored + 2 local changes.
//   Lesson from rounds 3/4: de-serializing the per-kt shfl chains made waves drift,
//   blew the per-XCD L2 working set (FETCH 25->400MB, WRITE 528MB->1.05GB), slower.
//   The per-kt cross-lane reduces PACE the waves; keep them. Changes this round:
//     (a) exp2 softmax with log2e folded into Q scale (pure VALU thinning, same
//         positions, same memory behavior, exact same softmax).
//     (b) head<->XCD pinning: head = dispatch-linear-id & 7, so each XCD's L2 holds
//         ONE kv-head's K+V (~1MB) instead of both (4MB). Targets the measured
//         L2-thrash mechanism.
//   prep:   x -> bf16; pack Wq|Wk|Wv transposed [n][c] bf16; Wo transposed [n][k] bf16
//   gemm<0>: xb @ WqkvT -> Qb [h][s][64] (x 0.125*log2e, +bq), Kb (+bk), VTb [h][64][s] (+bv)
//   attn:   grid 2048 blocks (256 q-tiles x 8 heads, XCD-pinned), 4 waves each own a
//           1024-key quarter; per-kt online softmax with cross-lane shfl reduces
//           (the pacing governor); phase2 recomputes S, LDS round-trip for the
//           P C->A layout transform, PV from global V^T (L2-resident), coalesced
//           fp32 dwordx4 att stores.
//   gemm<1>: OAb @ WobT + bo -> out fp32
// MFMA 16x16x32 bf16 layouts:
//   A: lane holds A[m=lane&15][k=quad*8+j]   B: B[k=quad*8+j][n=lane&15]
//   C/D: D[row=quad*4+reg][col=lane&15]

#define DIM   768
#define Sc    4096
// 0.125 * log2(e): QK^T scores land in log2 domain, softmax via exp2
#define QSCALE 0.180336880111120419f

typedef __bf16 bfrag __attribute__((ext_vector_type(8)));
typedef float  facc  __attribute__((ext_vector_type(4)));

#define MFMA_BF16(a,b,c) __builtin_amdgcn_mfma_f32_16x16x32_bf16((a),(b),(c),0,0,0)

// ---------------------------------------------------------------- prep
__global__ __launch_bounds__(256) void prep_kernel(
    const float* __restrict__ x,  const float* __restrict__ Wq,
    const float* __restrict__ Wk, const float* __restrict__ Wv,
    const float* __restrict__ Wo,
    __bf16* __restrict__ xb, __bf16* __restrict__ WqkvT, __bf16* __restrict__ WobT)
{
  int i = blockIdx.x * 256 + threadIdx.x;
  const int NX = Sc * DIM;      // 3145728
  const int NW = DIM * DIM;     // 589824
  if (i < NX) { xb[i] = (__bf16)x[i]; return; }
  i -= NX;
  if (i < NW) {                 // WqkvT[n][c]
    int n = i / DIM, c = i - n * DIM;
    float v;
    if (n < 512)      v = Wq[c * 512 + n];
    else if (n < 640) v = Wk[c * 128 + (n - 512)];
    else              v = Wv[c * 128 + (n - 640)];
    WqkvT[i] = (__bf16)v;
    return;
  }
  i -= NW;
  {                             // WobT[n][k], n<768, k<512
    int n = i / 512, k = i - n * 512;
    WobT[i] = (__bf16)Wo[k * DIM + n];
  }
}

// ---------------------------------------------------------------- gemm
// C[M=4096, N] = A[M,Kd] @ BT[N,Kd]^T. 64x64 block tile, 4 waves x (16r x 64c), BK=64.
// MODE 0: QKV epilogue (scatter to Qb/Kb/VTb, bias, Q scale QSCALE). MODE 1: fp32 out + b0.
template<int MODE>
__global__ __launch_bounds__(256) void gemm_kernel(
    const __bf16* __restrict__ A, const __bf16* __restrict__ BT, int Kd,
    const float* __restrict__ b0, const float* __restrict__ b1, const float* __restrict__ b2,
    __bf16* __restrict__ Qb, __bf16* __restrict__ Kb, __bf16* __restrict__ VTb,
    float* __restrict__ Cout)
{
  const int tid  = threadIdx.x;
  const int w    = tid >> 6;
  const int lane = tid & 63;
  const int i16  = lane & 15;
  const int quad = lane >> 4;
  const int n0   = blockIdx.x * 64;
  const int m0   = blockIdx.y * 64;

  __shared__ __attribute__((aligned(16))) __bf16 Al[64 * 72];
  __shared__ __attribute__((aligned(16))) __bf16 Bl[64 * 72];

  facc acc[4];
#pragma unroll
  for (int nt = 0; nt < 4; ++nt) acc[nt] = (facc){0.f, 0.f, 0.f, 0.f};

  const int nkt = Kd >> 6;
  for (int kt = 0; kt < nkt; ++kt) {
#pragma unroll
    for (int it = 0; it < 2; ++it) {       // A tile: 64 rows x 64k = 512 x 16B chunks
      int idx = tid + it * 256;
      int r = idx >> 3, ch = idx & 7;
      *(uint4*)&Al[r * 72 + ch * 8] =
          *(const uint4*)(A + (size_t)(m0 + r) * Kd + (kt * 64 + ch * 8));
    }
#pragma unroll
    for (int it = 0; it < 2; ++it) {       // BT tile
      int idx = tid + it * 256;
      int r = idx >> 3, ch = idx & 7;
      *(uint4*)&Bl[r * 72 + ch * 8] =
          *(const uint4*)(BT + (size_t)(n0 + r) * Kd + (kt * 64 + ch * 8));
    }
    __syncthreads();
#pragma unroll
    for (int ks = 0; ks < 2; ++ks) {
      bfrag a = *(const bfrag*)&Al[(w * 16 + i16) * 72 + ks * 32 + quad * 8];
#pragma unroll
      for (int nt = 0; nt < 4; ++nt) {
        bfrag b = *(const bfrag*)&Bl[(nt * 16 + i16) * 72 + ks * 32 + quad * 8];
        acc[nt] = MFMA_BF16(a, b, acc[nt]);
      }
    }
    __syncthreads();
  }

#pragma unroll
  for (int nt = 0; nt < 4; ++nt) {
    const int n = n0 + nt * 16 + i16;
    const int rbase = m0 + w * 16 + quad * 4;
    if (MODE == 0) {
      float bias;
      if (n < 512)      bias = b0[n];
      else if (n < 640) bias = b1[n - 512];
      else              bias = b2[n - 640];
#pragma unroll
      for (int reg = 0; reg < 4; ++reg) {
        float v = acc[nt][reg] + bias;
        int row = rbase + reg;
        if (n < 512) {                    // Q: fold 1/sqrt(64) * log2(e)
          int hh = n >> 6, d = n & 63;
          Qb[((size_t)hh * Sc + row) * 64 + d] = (__bf16)(v * QSCALE);
        } else if (n < 640) {             // K
          int hh = (n - 512) >> 6, d = n & 63;
          Kb[((size_t)hh * Sc + row) * 64 + d] = (__bf16)v;
        } else {                          // V stored transposed: VT[h][d][s]
          int hh = (n - 640) >> 6, d = n & 63;
          VTb[(size_t)hh * 64 * Sc + (size_t)d * Sc + row] = (__bf16)v;
        }
      }
    } else {
      float bias = b0[n];
#pragma unroll
      for (int reg = 0; reg < 4; ++reg)
        Cout[(size_t)(rbase + reg) * DIM + n] = acc[nt][reg] + bias;
    }
  }
}

// ---------------------------------------------------------------- attention
// grid 2048 blocks = (256 q-tiles, 8 heads), remapped so head = linear-id & 7
// (XCD-pinned). 256 thr = 4 waves; wave w owns keys [w*1024, (w+1)*1024).
// No barriers inside the K loops. Per-kt cross-lane reduces retained (pacing).
#define PFSTRIDE 68            // fp32 row stride (64 + 4 pad)
#define PFWAVE   (16 * PFSTRIDE + 4)   // 1092: per-wave region, +4 breaks w-stride conflicts

__global__ __launch_bounds__(256, 6) void attn_kernel(
    const __bf16* __restrict__ Qb, const __bf16* __restrict__ Kb,
    const __bf16* __restrict__ VTb,
    float* __restrict__ att, __bf16* __restrict__ OAb)
{
  const int tid  = threadIdx.x;
  const int w    = tid >> 6;
  const int lane = tid & 63;
  const int i16  = lane & 15;
  const int quad = lane >> 4;
  // XCD pinning: hardware round-robins dispatch-linear id over 8 XCDs, so
  // head = flat & 7 puts all of head h's blocks on XCD h -> per-XCD L2 holds
  // one kv-head's K+V (~1MB) instead of both (4MB).
  const int flat = blockIdx.x + (blockIdx.y << 8);
  const int h    = flat & 7;
  const int q0   = (flat >> 3) * 16;
  const int kvh  = h >> 2;          // n_rep = 4

  __shared__ __attribute__((aligned(16))) float Pf[4 * PFWAVE];  // ~17.5 KB
  __shared__ float SM[4][16], SL[4][16];

  const __bf16* Kbase = Kb  + (size_t)kvh * Sc * 64;
  const __bf16* Vbase = VTb + (size_t)kvh * 64 * Sc;

  // Q A-fragments (already scaled by 0.125*log2e), 16 rows
  bfrag qf[2];
#pragma unroll
  for (int ks = 0; ks < 2; ++ks)
    qf[ks] = *(const bfrag*)(Qb + ((size_t)h * Sc + q0 + i16) * 64 + ks * 32 + quad * 8);

  float mrun[4], lrun[4];
#pragma unroll
  for (int r = 0; r < 4; ++r) { mrun[r] = -1e30f; lrun[r] = 0.f; }

  const int key0 = w * 1024;

  // ---------------- phase 1: partial row max / sum over this wave's quarter ----
  for (int kt = 0; kt < 16; ++kt) {
    const int kb0 = key0 + kt * 64;
    facc s[4];
#pragma unroll
    for (int nt = 0; nt < 4; ++nt) s[nt] = (facc){0.f, 0.f, 0.f, 0.f};
#pragma unroll
    for (int ks = 0; ks < 2; ++ks)
#pragma unroll
      for (int nt = 0; nt < 4; ++nt) {
        bfrag kf = *(const bfrag*)(Kbase + (size_t)(kb0 + nt * 16 + i16) * 64 + ks * 32 + quad * 8);
        s[nt] = MFMA_BF16(qf[ks], kf, s[nt]);
      }
#pragma unroll
    for (int r = 0; r < 4; ++r) {
      float tm = fmaxf(fmaxf(s[0][r], s[1][r]), fmaxf(s[2][r], s[3][r]));
      tm = fmaxf(tm, __shfl_xor(tm, 1));
      tm = fmaxf(tm, __shfl_xor(tm, 2));
      tm = fmaxf(tm, __shfl_xor(tm, 4));
      tm = fmaxf(tm, __shfl_xor(tm, 8));
      float mnew = fmaxf(mrun[r], tm);
      float ts = exp2f(s[0][r] - mnew) + exp2f(s[1][r] - mnew)
               + exp2f(s[2][r] - mnew) + exp2f(s[3][r] - mnew);
      ts += __shfl_xor(ts, 1);
      ts += __shfl_xor(ts, 2);
      ts += __shfl_xor(ts, 4);
      ts += __shfl_xor(ts, 8);
      lrun[r] = lrun[r] * exp2f(mrun[r] - mnew) + ts;
      mrun[r] = mnew;
    }
  }

  // ---------------- combine stats across the 4 waves ----------------
  if (i16 == 0) {
#pragma unroll
    for (int r = 0; r < 4; ++r) { SM[w][quad * 4 + r] = mrun[r]; SL[w][quad * 4 + r] = lrun[r]; }
  }
  __syncthreads();
  float mglob[4], linv[4];
#pragma unroll
  for (int r = 0; r < 4; ++r) {
    const int rr = quad * 4 + r;
    float m0v = SM[0][rr], m1v = SM[1][rr], m2v = SM[2][rr], m3v = SM[3][rr];
    float mg = fmaxf(fmaxf(m0v, m1v), fmaxf(m2v, m3v));
    float lg = SL[0][rr] * exp2f(m0v - mg) + SL[1][rr] * exp2f(m1v - mg)
             + SL[2][rr] * exp2f(m2v - mg) + SL[3][rr] * exp2f(m3v - mg);
    mglob[r] = mg;
    linv[r]  = 1.f / lg;
  }

  facc oacc[4];
#pragma unroll
  for (int nt = 0; nt < 4; ++nt) oacc[nt] = (facc){0.f, 0.f, 0.f, 0.f};

  float* attb = att + (size_t)h * Sc * Sc;
  float* Pw   = Pf + w * PFWAVE;

  // ---------------- phase 2: recompute S, write att, PV ----------------
  for (int kt = 0; kt < 16; ++kt) {
    const int kb0 = key0 + kt * 64;
    facc s[4];
#pragma unroll
    for (int nt = 0; nt < 4; ++nt) s[nt] = (facc){0.f, 0.f, 0.f, 0.f};
#pragma unroll
    for (int ks = 0; ks < 2; ++ks)
#pragma unroll
      for (int nt = 0; nt < 4; ++nt) {
        bfrag kf = *(const bfrag*)(Kbase + (size_t)(kb0 + nt * 16 + i16) * 64 + ks * 32 + quad * 8);
        s[nt] = MFMA_BF16(qf[ks], kf, s[nt]);
      }
    // normalized probabilities -> per-wave fp32 LDS tile (C-layout writes)
#pragma unroll
    for (int nt = 0; nt < 4; ++nt)
#pragma unroll
      for (int r = 0; r < 4; ++r)
        Pw[(quad * 4 + r) * PFSTRIDE + nt * 16 + i16] =
            exp2f(s[nt][r] - mglob[r]) * linv[r];
    // A-layout fragments out of the same tile (same wave: no barrier)
    bfrag pa[2];
#pragma unroll
    for (int ks = 0; ks < 2; ++ks) {
      facc p0 = *(const facc*)&Pw[i16 * PFSTRIDE + ks * 32 + quad * 8];
      facc p1 = *(const facc*)&Pw[i16 * PFSTRIDE + ks * 32 + quad * 8 + 4];
      bfrag t;
      t[0] = (__bf16)p0[0]; t[1] = (__bf16)p0[1]; t[2] = (__bf16)p0[2]; t[3] = (__bf16)p0[3];
      t[4] = (__bf16)p1[0]; t[5] = (__bf16)p1[1]; t[6] = (__bf16)p1[2]; t[7] = (__bf16)p1[3];
      pa[ks] = t;
    }
    // PV with V^T fragments direct from global (L2-resident)
#pragma unroll
    for (int ks = 0; ks < 2; ++ks)
#pragma unroll
      for (int nt = 0; nt < 4; ++nt) {
        bfrag vf = *(const bfrag*)(Vbase + (size_t)(nt * 16 + i16) * Sc + kb0 + ks * 32 + quad * 8);
        oacc[nt] = MFMA_BF16(pa[ks], vf, oacc[nt]);
      }
    // coalesced att store: 4 x dwordx4, 256B per quad-row
#pragma unroll
    for (int it = 0; it < 4; ++it) {
      int flat2 = it * 64 + lane;
      int row = flat2 >> 4, c4 = flat2 & 15;
      facc v = *(const facc*)&Pw[row * PFSTRIDE + c4 * 4];
      *(facc*)&attb[(size_t)(q0 + row) * Sc + kb0 + c4 * 4] = v;
    }
  }

  // ---------------- reduce O partials across waves (reuse Pf) ----------------
#pragma unroll
  for (int nt = 0; nt < 4; ++nt)
#pragma unroll
    for (int r = 0; r < 4; ++r)
      Pw[(quad * 4 + r) * PFSTRIDE + nt * 16 + i16] = oacc[nt][r];
  __syncthreads();
#pragma unroll
  for (int it = 0; it < 4; ++it) {
    int e = it * 256 + tid;
    int row = e >> 6, d = e & 63;
    float sum = Pf[0 * PFWAVE + row * PFSTRIDE + d] + Pf[1 * PFWAVE + row * PFSTRIDE + d]
              + Pf[2 * PFWAVE + row * PFSTRIDE + d] + Pf[3 * PFWAVE + row * PFSTRIDE + d];
    OAb[(size_t)(q0 + row) * 512 + h * 64 + d] = (__bf16)sum;
  }
}

// ---------------------------------------------------------------- launch
extern "C" void kernel_launch(void* const* d_in, const int* in_sizes, int n_in,
                              void* d_out, int out_size, void* d_ws, size_t ws_size,
                              hipStream_t stream) {
  const float* x  = (const float*)d_in[0];
  const float* Wq = (const float*)d_in[1];
  const float* bq = (const float*)d_in[2];
  const float* Wk = (const float*)d_in[3];
  const float* bk = (const float*)d_in[4];
  const float* Wv = (const float*)d_in[5];
  const float* bv = (const float*)d_in[6];
  const float* Wo = (const float*)d_in[7];
  const float* bo = (const float*)d_in[8];

  float* out = (float*)d_out;
  float* att = out + (size_t)Sc * DIM;   // outputs concatenated: out then att

  char* ws = (char*)d_ws;
  size_t off = 0;
  __bf16* xb    = (__bf16*)(ws + off); off += (size_t)Sc * DIM * 2;
  __bf16* WqkvT = (__bf16*)(ws + off); off += (size_t)DIM * DIM * 2;
  __bf16* WobT  = (__bf16*)(ws + off); off += (size_t)DIM * 512 * 2;
  __bf16* Qb    = (__bf16*)(ws + off); off += (size_t)8 * Sc * 64 * 2;
  __bf16* Kb    = (__bf16*)(ws + off); off += (size_t)2 * Sc * 64 * 2;
  __bf16* VTb   = (__bf16*)(ws + off); off += (size_t)2 * 64 * Sc * 2;
  __bf16* OAb   = (__bf16*)(ws + off); off += (size_t)Sc * 512 * 2;

  prep_kernel<<<16128, 256, 0, stream>>>(x, Wq, Wk, Wv, Wo, xb, WqkvT, WobT);
  gemm_kernel<0><<<dim3(12, 64), 256, 0, stream>>>(xb, WqkvT, 768, bq, bk, bv,
                                                   Qb, Kb, VTb, nullptr);
  attn_kernel<<<dim3(256, 8), 256, 0, stream>>>(Qb, Kb, VTb, att, OAb);
  gemm_kernel<1><<<dim3(12, 64), 256, 0, stream>>>(OAb, WobT, 512, bo, nullptr, nullptr,
                                                   nullptr, nullptr, nullptr, out);
}

// Round 4
// 864.285 us; speedup vs baseline: 1.1734x; 1.0164x over previous
//
#include <hip/hip_runtime.h>
#include <hip/hip_bf16.h>

// GQA block, MI355X/gfx950. Round 6: test cell (chains=0, pin=1) + raw v_exp.
//   A/B matrix so far: paced+unpinned 382us/F25MB; unpaced+unpinned 520us/F400MB;
//   paced+pinned 396us/F15MB. Pinning contains the K/V working set (one kv-head
//   ~1MB per XCD L2), so retry the de-serialized softmax under it:
//     (a) phase 1 keeps online stats PER-LANE (no per-kt dependent shfl chains,
//         ~13k cy/wave of ds_swizzle stall removed); one 8-shfl reduce at the end.
//     (b) exp2f -> __builtin_amdgcn_exp2f (round 5 showed libm exp2f emits a
//         range-fixup: VALUBusy 17->25%. The builtin is a bare v_exp_f32; softmax
//         args are <=0 so flush-to-zero semantics are exactly right).
//     (c) head<->XCD pinning kept (head = linear-id & 7).
//     (d) no setprio, V loads inline (minimize confounds on the structural axis).
//   prep:   x -> bf16; pack Wq|Wk|Wv transposed [n][c] bf16; Wo transposed [n][k] bf16
//   gemm<0>: xb @ WqkvT -> Qb [h][s][64] (x 0.125*log2e, +bq), Kb (+bk), VTb [h][64][s] (+bv)
//   gemm<1>: OAb @ WobT + bo -> out fp32
// MFMA 16x16x32 bf16 layouts:
//   A: lane holds A[m=lane&15][k=quad*8+j]   B: B[k=quad*8+j][n=lane&15]
//   C/D: D[row=quad*4+reg][col=lane&15]

#define DIM   768
#define Sc    4096
// 0.125 * log2(e): QK^T scores land in log2 domain, softmax via exp2
#define QSCALE 0.180336880111120419f
#define EXP2(x) __builtin_amdgcn_exp2f(x)

typedef __bf16 bfrag __attribute__((ext_vector_type(8)));
typedef float  facc  __attribute__((ext_vector_type(4)));

#define MFMA_BF16(a,b,c) __builtin_amdgcn_mfma_f32_16x16x32_bf16((a),(b),(c),0,0,0)

// ---------------------------------------------------------------- prep
__global__ __launch_bounds__(256) void prep_kernel(
    const float* __restrict__ x,  const float* __restrict__ Wq,
    const float* __restrict__ Wk, const float* __restrict__ Wv,
    const float* __restrict__ Wo,
    __bf16* __restrict__ xb, __bf16* __restrict__ WqkvT, __bf16* __restrict__ WobT)
{
  int i = blockIdx.x * 256 + threadIdx.x;
  const int NX = Sc * DIM;      // 3145728
  const int NW = DIM * DIM;     // 589824
  if (i < NX) { xb[i] = (__bf16)x[i]; return; }
  i -= NX;
  if (i < NW) {                 // WqkvT[n][c]
    int n = i / DIM, c = i - n * DIM;
    float v;
    if (n < 512)      v = Wq[c * 512 + n];
    else if (n < 640) v = Wk[c * 128 + (n - 512)];
    else              v = Wv[c * 128 + (n - 640)];
    WqkvT[i] = (__bf16)v;
    return;
  }
  i -= NW;
  {                             // WobT[n][k], n<768, k<512
    int n = i / 512, k = i - n * 512;
    WobT[i] = (__bf16)Wo[k * DIM + n];
  }
}

// ---------------------------------------------------------------- gemm
// C[M=4096, N] = A[M,Kd] @ BT[N,Kd]^T. 64x64 block tile, 4 waves x (16r x 64c), BK=64.
// MODE 0: QKV epilogue (scatter to Qb/Kb/VTb, bias, Q scale QSCALE). MODE 1: fp32 out + b0.
template<int MODE>
__global__ __launch_bounds__(256) void gemm_kernel(
    const __bf16* __restrict__ A, const __bf16* __restrict__ BT, int Kd,
    const float* __restrict__ b0, const float* __restrict__ b1, const float* __restrict__ b2,
    __bf16* __restrict__ Qb, __bf16* __restrict__ Kb, __bf16* __restrict__ VTb,
    float* __restrict__ Cout)
{
  const int tid  = threadIdx.x;
  const int w    = tid >> 6;
  const int lane = tid & 63;
  const int i16  = lane & 15;
  const int quad = lane >> 4;
  const int n0   = blockIdx.x * 64;
  const int m0   = blockIdx.y * 64;

  __shared__ __attribute__((aligned(16))) __bf16 Al[64 * 72];
  __shared__ __attribute__((aligned(16))) __bf16 Bl[64 * 72];

  facc acc[4];
#pragma unroll
  for (int nt = 0; nt < 4; ++nt) acc[nt] = (facc){0.f, 0.f, 0.f, 0.f};

  const int nkt = Kd >> 6;
  for (int kt = 0; kt < nkt; ++kt) {
#pragma unroll
    for (int it = 0; it < 2; ++it) {       // A tile: 64 rows x 64k = 512 x 16B chunks
      int idx = tid + it * 256;
      int r = idx >> 3, ch = idx & 7;
      *(uint4*)&Al[r * 72 + ch * 8] =
          *(const uint4*)(A + (size_t)(m0 + r) * Kd + (kt * 64 + ch * 8));
    }
#pragma unroll
    for (int it = 0; it < 2; ++it) {       // BT tile
      int idx = tid + it * 256;
      int r = idx >> 3, ch = idx & 7;
      *(uint4*)&Bl[r * 72 + ch * 8] =
          *(const uint4*)(BT + (size_t)(n0 + r) * Kd + (kt * 64 + ch * 8));
    }
    __syncthreads();
#pragma unroll
    for (int ks = 0; ks < 2; ++ks) {
      bfrag a = *(const bfrag*)&Al[(w * 16 + i16) * 72 + ks * 32 + quad * 8];
#pragma unroll
      for (int nt = 0; nt < 4; ++nt) {
        bfrag b = *(const bfrag*)&Bl[(nt * 16 + i16) * 72 + ks * 32 + quad * 8];
        acc[nt] = MFMA_BF16(a, b, acc[nt]);
      }
    }
    __syncthreads();
  }

#pragma unroll
  for (int nt = 0; nt < 4; ++nt) {
    const int n = n0 + nt * 16 + i16;
    const int rbase = m0 + w * 16 + quad * 4;
    if (MODE == 0) {
      float bias;
      if (n < 512)      bias = b0[n];
      else if (n < 640) bias = b1[n - 512];
      else              bias = b2[n - 640];
#pragma unroll
      for (int reg = 0; reg < 4; ++reg) {
        float v = acc[nt][reg] + bias;
        int row = rbase + reg;
        if (n < 512) {                    // Q: fold 1/sqrt(64) * log2(e)
          int hh = n >> 6, d = n & 63;
          Qb[((size_t)hh * Sc + row) * 64 + d] = (__bf16)(v * QSCALE);
        } else if (n < 640) {             // K
          int hh = (n - 512) >> 6, d = n & 63;
          Kb[((size_t)hh * Sc + row) * 64 + d] = (__bf16)v;
        } else {                          // V stored transposed: VT[h][d][s]
          int hh = (n - 640) >> 6, d = n & 63;
          VTb[(size_t)hh * 64 * Sc + (size_t)d * Sc + row] = (__bf16)v;
        }
      }
    } else {
      float bias = b0[n];
#pragma unroll
      for (int reg = 0; reg < 4; ++reg)
        Cout[(size_t)(rbase + reg) * DIM + n] = acc[nt][reg] + bias;
    }
  }
}

// ---------------------------------------------------------------- attention
// grid 2048 blocks = (256 q-tiles, 8 heads), remapped so head = linear-id & 7
// (XCD-pinned). 256 thr = 4 waves; wave w owns keys [w*1024, (w+1)*1024).
// No barriers inside the K loops.
#define PFSTRIDE 68            // fp32 row stride (64 + 4 pad)
#define PFWAVE   (16 * PFSTRIDE + 4)   // 1092: per-wave region, +4 breaks w-stride conflicts

__global__ __launch_bounds__(256, 6) void attn_kernel(
    const __bf16* __restrict__ Qb, const __bf16* __restrict__ Kb,
    const __bf16* __restrict__ VTb,
    float* __restrict__ att, __bf16* __restrict__ OAb)
{
  const int tid  = threadIdx.x;
  const int w    = tid >> 6;
  const int lane = tid & 63;
  const int i16  = lane & 15;
  const int quad = lane >> 4;
  // XCD pinning: hardware round-robins dispatch-linear id over 8 XCDs, so
  // head = flat & 7 puts all of head h's blocks on XCD h -> per-XCD L2 holds
  // one kv-head's K+V (~1MB) instead of both.
  const int flat = blockIdx.x + (blockIdx.y << 8);
  const int h    = flat & 7;
  const int q0   = (flat >> 3) * 16;
  const int kvh  = h >> 2;          // n_rep = 4

  __shared__ __attribute__((aligned(16))) float Pf[4 * PFWAVE];  // ~17.5 KB
  __shared__ float SM[4][16], SL[4][16];

  const __bf16* Kbase = Kb  + (size_t)kvh * Sc * 64;
  const __bf16* Vbase = VTb + (size_t)kvh * 64 * Sc;

  // Q A-fragments (already scaled by 0.125*log2e), 16 rows
  bfrag qf[2];
#pragma unroll
  for (int ks = 0; ks < 2; ++ks)
    qf[ks] = *(const bfrag*)(Qb + ((size_t)h * Sc + q0 + i16) * 64 + ks * 32 + quad * 8);

  const int key0 = w * 1024;

  // ---------------- phase 1: PER-LANE online stats over this wave's quarter ------
  // C layout: lane holds rows quad*4+r, cols nt*16+i16. Per-lane max/sum over this
  // lane's 4 columns per tile; cross-lane reduce ONCE after the loop.
  float mrun[4], lrun[4];
#pragma unroll
  for (int r = 0; r < 4; ++r) { mrun[r] = -1e30f; lrun[r] = 0.f; }

  for (int kt = 0; kt < 16; ++kt) {
    const int kb0 = key0 + kt * 64;
    facc s[4];
#pragma unroll
    for (int nt = 0; nt < 4; ++nt) s[nt] = (facc){0.f, 0.f, 0.f, 0.f};
#pragma unroll
    for (int ks = 0; ks < 2; ++ks)
#pragma unroll
      for (int nt = 0; nt < 4; ++nt) {
        bfrag kf = *(const bfrag*)(Kbase + (size_t)(kb0 + nt * 16 + i16) * 64 + ks * 32 + quad * 8);
        s[nt] = MFMA_BF16(qf[ks], kf, s[nt]);
      }
#pragma unroll
    for (int r = 0; r < 4; ++r) {
      float t0 = s[0][r], t1 = s[1][r], t2 = s[2][r], t3 = s[3][r];
      float tm   = fmaxf(fmaxf(t0, t1), fmaxf(t2, t3));
      float mnew = fmaxf(mrun[r], tm);
      float ts = EXP2(t0 - mnew) + EXP2(t1 - mnew)
               + EXP2(t2 - mnew) + EXP2(t3 - mnew);
      lrun[r] = lrun[r] * EXP2(mrun[r] - mnew) + ts;
      mrun[r] = mnew;
    }
  }

  // single cross-lane reduce (16 lanes sharing each row), then cross-wave combine
#pragma unroll
  for (int r = 0; r < 4; ++r) {
    float m = mrun[r];
    m = fmaxf(m, __shfl_xor(m, 1));
    m = fmaxf(m, __shfl_xor(m, 2));
    m = fmaxf(m, __shfl_xor(m, 4));
    m = fmaxf(m, __shfl_xor(m, 8));
    float l = lrun[r] * EXP2(mrun[r] - m);
    l += __shfl_xor(l, 1);
    l += __shfl_xor(l, 2);
    l += __shfl_xor(l, 4);
    l += __shfl_xor(l, 8);
    if (i16 == 0) { SM[w][quad * 4 + r] = m; SL[w][quad * 4 + r] = l; }
  }
  __syncthreads();

  float mglob[4], linv[4];
#pragma unroll
  for (int r = 0; r < 4; ++r) {
    const int rr = quad * 4 + r;
    float m0v = SM[0][rr], m1v = SM[1][rr], m2v = SM[2][rr], m3v = SM[3][rr];
    float mg = fmaxf(fmaxf(m0v, m1v), fmaxf(m2v, m3v));
    float lg = SL[0][rr] * EXP2(m0v - mg) + SL[1][rr] * EXP2(m1v - mg)
             + SL[2][rr] * EXP2(m2v - mg) + SL[3][rr] * EXP2(m3v - mg);
    mglob[r] = mg;
    linv[r]  = 1.f / lg;
  }

  facc oacc[4];
#pragma unroll
  for (int nt = 0; nt < 4; ++nt) oacc[nt] = (facc){0.f, 0.f, 0.f, 0.f};

  float* attb = att + (size_t)h * Sc * Sc;
  float* Pw   = Pf + w * PFWAVE;

  // ---------------- phase 2: recompute S, write att, PV ----------------
  for (int kt = 0; kt < 16; ++kt) {
    const int kb0 = key0 + kt * 64;
    facc s[4];
#pragma unroll
    for (int nt = 0; nt < 4; ++nt) s[nt] = (facc){0.f, 0.f, 0.f, 0.f};
#pragma unroll
    for (int ks = 0; ks < 2; ++ks)
#pragma unroll
      for (int nt = 0; nt < 4; ++nt) {
        bfrag kf = *(const bfrag*)(Kbase + (size_t)(kb0 + nt * 16 + i16) * 64 + ks * 32 + quad * 8);
        s[nt] = MFMA_BF16(qf[ks], kf, s[nt]);
      }
    // normalized probabilities -> per-wave fp32 LDS tile (C-layout writes)
#pragma unroll
    for (int nt = 0; nt < 4; ++nt)
#pragma unroll
      for (int r = 0; r < 4; ++r)
        Pw[(quad * 4 + r) * PFSTRIDE + nt * 16 + i16] =
            EXP2(s[nt][r] - mglob[r]) * linv[r];
    // A-layout fragments out of the same tile (same wave: no barrier)
    bfrag pa[2];
#pragma unroll
    for (int ks = 0; ks < 2; ++ks) {
      facc p0 = *(const facc*)&Pw[i16 * PFSTRIDE + ks * 32 + quad * 8];
      facc p1 = *(const facc*)&Pw[i16 * PFSTRIDE + ks * 32 + quad * 8 + 4];
      bfrag t;
      t[0] = (__bf16)p0[0]; t[1] = (__bf16)p0[1]; t[2] = (__bf16)p0[2]; t[3] = (__bf16)p0[3];
      t[4] = (__bf16)p1[0]; t[5] = (__bf16)p1[1]; t[6] = (__bf16)p1[2]; t[7] = (__bf16)p1[3];
      pa[ks] = t;
    }
    // PV with V^T fragments direct from global (L2-resident)
#pragma unroll
    for (int ks = 0; ks < 2; ++ks)
#pragma unroll
      for (int nt = 0; nt < 4; ++nt) {
        bfrag vf = *(const bfrag*)(Vbase + (size_t)(nt * 16 + i16) * Sc + kb0 + ks * 32 + quad * 8);
        oacc[nt] = MFMA_BF16(pa[ks], vf, oacc[nt]);
      }
    // coalesced att store: 4 x dwordx4, 256B per quad-row
#pragma unroll
    for (int it = 0; it < 4; ++it) {
      int flat2 = it * 64 + lane;
      int row = flat2 >> 4, c4 = flat2 & 15;
      facc v = *(const facc*)&Pw[row * PFSTRIDE + c4 * 4];
      *(facc*)&attb[(size_t)(q0 + row) * Sc + kb0 + c4 * 4] = v;
    }
  }

  // ---------------- reduce O partials across waves (reuse Pf) ----------------
#pragma unroll
  for (int nt = 0; nt < 4; ++nt)
#pragma unroll
    for (int r = 0; r < 4; ++r)
      Pw[(quad * 4 + r) * PFSTRIDE + nt * 16 + i16] = oacc[nt][r];
  __syncthreads();
#pragma unroll
  for (int it = 0; it < 4; ++it) {
    int e = it * 256 + tid;
    int row = e >> 6, d = e & 63;
    float sum = Pf[0 * PFWAVE + row * PFSTRIDE + d] + Pf[1 * PFWAVE + row * PFSTRIDE + d]
              + Pf[2 * PFWAVE + row * PFSTRIDE + d] + Pf[3 * PFWAVE + row * PFSTRIDE + d];
    OAb[(size_t)(q0 + row) * 512 + h * 64 + d] = (__bf16)sum;
  }
}

// ---------------------------------------------------------------- launch
extern "C" void kernel_launch(void* const* d_in, const int* in_sizes, int n_in,
                              void* d_out, int out_size, void* d_ws, size_t ws_size,
                              hipStream_t stream) {
  const float* x  = (const float*)d_in[0];
  const float* Wq = (const float*)d_in[1];
  const float* bq = (const float*)d_in[2];
  const float* Wk = (const float*)d_in[3];
  const float* bk = (const float*)d_in[4];
  const float* Wv = (const float*)d_in[5];
  const float* bv = (const float*)d_in[6];
  const float* Wo = (const float*)d_in[7];
  const float* bo = (const float*)d_in[8];

  float* out = (float*)d_out;
  float* att = out + (size_t)Sc * DIM;   // outputs concatenated: out then att

  char* ws = (char*)d_ws;
  size_t off = 0;
  __bf16* xb    = (__bf16*)(ws + off); off += (size_t)Sc * DIM * 2;
  __bf16* WqkvT = (__bf16*)(ws + off); off += (size_t)DIM * DIM * 2;
  __bf16* WobT  = (__bf16*)(ws + off); off += (size_t)DIM * 512 * 2;
  __bf16* Qb    = (__bf16*)(ws + off); off += (size_t)8 * Sc * 64 * 2;
  __bf16* Kb    = (__bf16*)(ws + off); off += (size_t)2 * Sc * 64 * 2;
  __bf16* VTb   = (__bf16*)(ws + off); off += (size_t)2 * 64 * Sc * 2;
  __bf16* OAb   = (__bf16*)(ws + off); off += (size_t)Sc * 512 * 2;

  prep_kernel<<<16128, 256, 0, stream>>>(x, Wq, Wk, Wv, Wo, xb, WqkvT, WobT);
  gemm_kernel<0><<<dim3(12, 64), 256, 0, stream>>>(xb, WqkvT, 768, bq, bk, bv,
                                                   Qb, Kb, VTb, nullptr);
  attn_kernel<<<dim3(256, 8), 256, 0, stream>>>(Qb, Kb, VTb, att, OAb);
  gemm_kernel<1><<<dim3(12, 64), 256, 0, stream>>>(OAb, WobT, 512, bo, nullptr, nullptr,
                                                   nullptr, nullptr, nullptr, out);
}